// Round 1
// 571.138 us; speedup vs baseline: 1.1143x; 1.1143x over previous
//
#include <hip/hip_runtime.h>

// Resample2d (Flownet2-style) bilinear warp.
// feature: [B,C,H,W] fp32, flow: [B,2,H,W] fp32, out: [B,C,H,W] fp32.
//
// R2: LDS-staged tile gather. Previous version was vector-memory LINE-LOOKUP
// bound: per-pixel-independent N(0,3) flow makes every tap load touch ~1
// distinct 64B line per lane (64 lines per wave-load -> ~64 cyc each; 917k
// lookups/CU ~= the whole 377us). Fix: stage a 64x64-pixel window (+12/11
// halo, zero-padded) of CPB=2 channel planes into LDS with coalesced float2
// loads, gather taps from LDS (divergent LDS addressing costs only bank
// conflicts). Gaussian-tail taps outside the staged window take a rare
// global fallback branch. XCD-chunked block swizzle keeps halo re-reads
// L2-resident.

#define Bv 2
#define Cv 64
#define Hv 512
#define Wv 896
#define HWsz (Hv * Wv)

#define TILE 64
#define CPB 2                  // channels per block
#define NCG (Cv / CPB)         // 32 channel groups
#define SW 90                  // staged cols == LDS row stride (floats)
#define SH 88                  // staged rows
#define XOFF 12                // xs = tx0 - 12 (even -> float2-aligned stage loads)
#define YOFF 11                // ys = ty0 - 11
#define NTX (Wv / TILE)        // 14
#define NTY (Hv / TILE)        // 8
#define NTILES (NTX * NTY)     // 112
#define NBLK (Bv * NCG * NTILES)  // 7168 (divisible by 8 -> bijective XCD swizzle)
#define THREADS 512
#define NWAVES (THREADS / 64)

__global__ __launch_bounds__(THREADS) void resample2d_kernel(
    const float* __restrict__ feature,
    const float* __restrict__ flow,
    float* __restrict__ out) {
    __shared__ float smem[CPB][SH * SW];  // 2*88*90*4 = 63,360 B (<64KB static)

    // XCD-chunked swizzle: each XCD gets a contiguous raster of tiles for a
    // contiguous set of channel-groups -> halo re-reads hit that XCD's L2.
    const int orig = blockIdx.x;
    const int wid = (orig & 7) * (NBLK / 8) + (orig >> 3);
    const int txi = wid % NTX;
    const int t2 = wid / NTX;
    const int tyi = t2 % NTY;
    const int zb = t2 / NTY;
    const int b = zb / NCG;
    const int c0 = (zb % NCG) * CPB;

    const int tx0 = txi * TILE;
    const int ty0 = tyi * TILE;
    const int xs = tx0 - XOFF;  // even by construction
    const int ys = ty0 - YOFF;

    const int tid = threadIdx.x;
    const int lane = tid & 63;
    const int wv = tid >> 6;

    const float* __restrict__ fbase = feature + ((size_t)b * Cv + c0) * HWsz;

    // ---------------- stage CPB channel windows into LDS ----------------
    const bool interior = (xs >= 0) & (xs + SW <= Wv) & (ys >= 0) & (ys + SH <= Hv);
    if (lane < SW / 2) {  // 45 lanes; one float2 (2 cols) per lane per row
        if (interior) {
            for (int rr = wv; rr < CPB * SH; rr += NWAVES) {
                const int c = (rr >= SH) ? 1 : 0;
                const int r = rr - c * SH;
                const float2 val = *(const float2*)(fbase + (size_t)c * HWsz +
                                                    (size_t)(ys + r) * Wv + xs + 2 * lane);
                *(float2*)(&smem[c][r * SW + 2 * lane]) = val;
            }
        } else {
            // edge tiles: zero-fill out-of-image cells (this IS the
            // zero-weight semantics of the reference for OOB taps)
            for (int rr = wv; rr < CPB * SH; rr += NWAVES) {
                const int c = (rr >= SH) ? 1 : 0;
                const int r = rr - c * SH;
                const int gy = ys + r;
                const int gx0 = xs + 2 * lane;
                float a0 = 0.0f, a1 = 0.0f;
                if ((unsigned)gy < (unsigned)Hv) {
                    const float* src = fbase + (size_t)c * HWsz + (size_t)gy * Wv;
                    if ((unsigned)gx0 < (unsigned)Wv) a0 = src[gx0];
                    if ((unsigned)(gx0 + 1) < (unsigned)Wv) a1 = src[gx0 + 1];
                }
                smem[c][r * SW + 2 * lane] = a0;
                smem[c][r * SW + 2 * lane + 1] = a1;
            }
        }
    }
    __syncthreads();

    // ---------------- compute ----------------
    const int px = tx0 + lane;
    const float* __restrict__ flb = flow + (size_t)b * 2 * HWsz;
    float* __restrict__ ob = out + ((size_t)b * Cv + c0) * HWsz;

#pragma unroll 2
    for (int k = 0; k < TILE / NWAVES; ++k) {
        const int y = ty0 + wv * (TILE / NWAVES) + k;
        const int pix = y * Wv + px;
        const float u = flb[pix];
        const float v = flb[HWsz + pix];
        const float gx = u + (float)px;
        const float gy = v + (float)y;
        const float x0f = floorf(gx);
        const float y0f = floorf(gy);
        const float wx = gx - x0f;
        const float wy = gy - y0f;
        const int x0 = (int)x0f;
        const int y0 = (int)y0f;
        const float omx = 1.0f - wx;
        const float omy = 1.0f - wy;
        const float w00 = omx * omy;
        const float w10 = wx * omy;
        const float w01 = omx * wy;
        const float w11 = wx * wy;

        const int lx = x0 - xs;
        const int ly = y0 - ys;
        // taps (lx..lx+1, ly..ly+1) all inside staged window?
        const bool inwin = ((unsigned)lx <= (unsigned)(SW - 2)) &
                           ((unsigned)ly <= (unsigned)(SH - 2));
        const int a = ly * SW + lx;

        float t00[CPB], t10[CPB], t01[CPB], t11[CPB];
        if (inwin) {
#pragma unroll
            for (int c = 0; c < CPB; ++c) {
                t00[c] = smem[c][a];
                t10[c] = smem[c][a + 1];
                t01[c] = smem[c][a + SW];
                t11[c] = smem[c][a + SW + 1];
            }
        } else {
            // rare Gaussian-tail fallback: full reference semantics
            const int x1 = x0 + 1, y1 = y0 + 1;
            const bool vx0 = (unsigned)x0 < (unsigned)Wv;
            const bool vx1 = (unsigned)x1 < (unsigned)Wv;
            const bool vy0 = (unsigned)y0 < (unsigned)Hv;
            const bool vy1 = (unsigned)y1 < (unsigned)Hv;
            const int cx0 = min(max(x0, 0), Wv - 1);
            const int cx1 = min(max(x1, 0), Wv - 1);
            const int cy0 = min(max(y0, 0), Hv - 1);
            const int cy1 = min(max(y1, 0), Hv - 1);
#pragma unroll
            for (int c = 0; c < CPB; ++c) {
                const float* f = fbase + (size_t)c * HWsz;
                t00[c] = (vx0 & vy0) ? f[cy0 * Wv + cx0] : 0.0f;
                t10[c] = (vx1 & vy0) ? f[cy0 * Wv + cx1] : 0.0f;
                t01[c] = (vx0 & vy1) ? f[cy1 * Wv + cx0] : 0.0f;
                t11[c] = (vx1 & vy1) ? f[cy1 * Wv + cx1] : 0.0f;
            }
        }
#pragma unroll
        for (int c = 0; c < CPB; ++c) {
            ob[(size_t)c * HWsz + pix] =
                t00[c] * w00 + t10[c] * w10 + t01[c] * w01 + t11[c] * w11;
        }
    }
}

extern "C" void kernel_launch(void* const* d_in, const int* in_sizes, int n_in,
                              void* d_out, int out_size, void* d_ws, size_t ws_size,
                              hipStream_t stream) {
    const float* feature = (const float*)d_in[0];
    const float* flow = (const float*)d_in[1];
    float* out = (float*)d_out;

    dim3 block(THREADS, 1, 1);
    dim3 grid(NBLK, 1, 1);
    resample2d_kernel<<<grid, block, 0, stream>>>(feature, flow, out);
}

// Round 2
// 467.565 us; speedup vs baseline: 1.3612x; 1.2215x over previous
//
#include <hip/hip_runtime.h>

// Resample2d (Flownet2-style) bilinear warp.
// feature: [B,C,H,W] fp32, flow: [B,2,H,W] fp32, out: [B,C,H,W] fp32.
//
// R3: attack the 415-cyc/wave-iteration latency stall seen in R2's counters
// (VALUBusy 23%, HBM 19%, LDS ~50cyc/iter -> nothing saturated = dependency
// stalls). Changes:
//  - CPB 2->4 with channel-interleaved LDS (smem[site][4]): one aligned
//    ds_read_b128 per tap serves 4 channels (4 LDS instrs/pixel vs 8 for 2ch).
//    Task count halves. 126.7KB dynamic LDS, 1024-thread block, 16 waves/CU.
//  - Flow loads + weight/address math hoisted ABOVE the barrier: their HBM
//    latency hides under the staging loop.
//  - Explicit 2-deep pipeline in consume: issue taps for iter k+2 while
//    combining iter k (LDS latency covered by independent b128 reads).
//  - Staging: one site per lane -> conflict-free consecutive ds_write_b128.
//  - Nontemporal output stores (write-once data stops evicting halo from L2).

#define Bv 2
#define Cv 64
#define Hv 512
#define Wv 896
#define HWsz (Hv * Wv)

#define TILE 64
#define CPB 4                  // channels per block (one float4 lane in LDS)
#define NCG (Cv / CPB)         // 16 channel groups
#define SW 90                  // staged cols (window width)
#define SH 88                  // staged rows
#define XOFF 12                // xs = tx0 - 12
#define YOFF 11                // ys = ty0 - 11
#define NSITES (SH * SW)       // 7920
#define NTX (Wv / TILE)        // 14
#define NTY (Hv / TILE)        // 8
#define NTILES (NTX * NTY)     // 112
#define NBLK (Bv * NCG * NTILES)  // 3584 (divisible by 8 -> bijective XCD swizzle)
#define THREADS 1024
#define NW (THREADS / 64)      // 16 waves
#define KITERS (TILE * TILE / THREADS)  // 4 pixel-iterations per thread
#define LDS_BYTES (NSITES * CPB * 4)    // 126,720 B

__global__ __launch_bounds__(THREADS) void resample2d_kernel(
    const float* __restrict__ feature,
    const float* __restrict__ flow,
    float* __restrict__ out) {
    extern __shared__ float smem[];  // [NSITES][CPB]

    // XCD-chunked swizzle (bijective: NBLK % 8 == 0): neighboring tiles of the
    // same channel planes land on the same XCD -> halo re-reads are L2 hits.
    const int orig = blockIdx.x;
    const int wid = (orig & 7) * (NBLK / 8) + (orig >> 3);
    const int txi = wid % NTX;
    const int t2 = wid / NTX;
    const int tyi = t2 % NTY;
    const int zb = t2 / NTY;
    const int b = zb / NCG;
    const int c0 = (zb % NCG) * CPB;

    const int tx0 = txi * TILE;
    const int ty0 = tyi * TILE;
    const int xs = tx0 - XOFF;
    const int ys = ty0 - YOFF;

    const int tid = threadIdx.x;
    const int lane = tid & 63;
    const int wv = tid >> 6;

    const float* __restrict__ fbase = feature + ((size_t)b * Cv + c0) * HWsz;
    const float* __restrict__ flb = flow + (size_t)b * 2 * HWsz;
    float* __restrict__ ob = out + ((size_t)b * Cv + c0) * HWsz;

    // ---- Phase A: issue flow loads for all KITERS rows (independent of LDS;
    // latency hides under the staging loop below).
    const int px = tx0 + lane;
    float u[KITERS], v[KITERS];
    int pixk[KITERS];
#pragma unroll
    for (int k = 0; k < KITERS; ++k) {
        const int y = ty0 + wv + NW * k;
        pixk[k] = y * Wv + px;
        u[k] = flb[pixk[k]];
        v[k] = flb[HWsz + pixk[k]];
    }

    // ---- Phase B: stage CPB channel planes, channel-interleaved.
    // One site per lane: consecutive lanes -> consecutive 16B ds_write_b128
    // (conflict-free). Global loads per channel are 4B-stride coalesced.
    const bool interior = (xs >= 0) & (xs + SW <= Wv) & (ys >= 0) & (ys + SH <= Hv);
    if (interior) {
#pragma unroll
        for (int k = 0; k < 8; ++k) {
            const int p = tid + THREADS * k;
            if (p < NSITES) {
                const int r = p / SW;
                const int xx = p - r * SW;
                const float* src = fbase + (size_t)(ys + r) * Wv + (xs + xx);
                float4 val;
                val.x = src[0];
                val.y = src[HWsz];
                val.z = src[2 * HWsz];
                val.w = src[3 * HWsz];
                *(float4*)(&smem[(size_t)p * CPB]) = val;
            }
        }
    } else {
        // edge tiles: zero-fill out-of-image cells (== reference's zero-weight
        // semantics for OOB taps)
#pragma unroll
        for (int k = 0; k < 8; ++k) {
            const int p = tid + THREADS * k;
            if (p < NSITES) {
                const int r = p / SW;
                const int xx = p - r * SW;
                const int gy = ys + r;
                const int gx = xs + xx;
                float4 val = make_float4(0.0f, 0.0f, 0.0f, 0.0f);
                if (((unsigned)gy < (unsigned)Hv) & ((unsigned)gx < (unsigned)Wv)) {
                    const float* src = fbase + (size_t)gy * Wv + gx;
                    val.x = src[0];
                    val.y = src[HWsz];
                    val.z = src[2 * HWsz];
                    val.w = src[3 * HWsz];
                }
                *(float4*)(&smem[(size_t)p * CPB]) = val;
            }
        }
    }

    // ---- Phase C: weights + clamped LDS addresses (flow has arrived by now;
    // VALU work overlaps the staging drain).
    float w00[KITERS], w10[KITERS], w01[KITERS], w11[KITERS];
    int ac[KITERS];
    bool inwin[KITERS];
#pragma unroll
    for (int k = 0; k < KITERS; ++k) {
        const int y = ty0 + wv + NW * k;
        const float gx = u[k] + (float)px;
        const float gy = v[k] + (float)y;
        const float x0f = floorf(gx);
        const float y0f = floorf(gy);
        const float wx = gx - x0f;
        const float wy = gy - y0f;
        const float omx = 1.0f - wx;
        const float omy = 1.0f - wy;
        w00[k] = omx * omy;
        w10[k] = wx * omy;
        w01[k] = omx * wy;
        w11[k] = wx * wy;
        const int lx = (int)x0f - xs;
        const int ly = (int)y0f - ys;
        inwin[k] = ((unsigned)lx <= (unsigned)(SW - 2)) &
                   ((unsigned)ly <= (unsigned)(SH - 2));
        const int lxc = min(max(lx, 0), SW - 2);
        const int lyc = min(max(ly, 0), SH - 2);
        ac[k] = (lyc * SW + lxc) * CPB;  // float index; always in-bounds
    }

    __syncthreads();

    // ---- Phase D: 2-deep pipelined gather+combine.
    // READ: 4 aligned ds_read_b128 (taps 00,10,01,11 for 4 channels).
#define READ(T, K)                                                  \
    do {                                                            \
        const int a_ = ac[K];                                       \
        T[0] = *(const float4*)(&smem[a_]);                         \
        T[1] = *(const float4*)(&smem[a_ + CPB]);                   \
        T[2] = *(const float4*)(&smem[a_ + SW * CPB]);              \
        T[3] = *(const float4*)(&smem[a_ + SW * CPB + CPB]);        \
    } while (0)

#define CONSUME(T, K)                                                         \
    do {                                                                      \
        if (!inwin[K]) { /* rare Gaussian-tail fallback (execz-skipped) */    \
            const float gx_ = u[K] + (float)px;                               \
            const float gy_ = v[K] + (float)(ty0 + wv + NW * (K));            \
            const int x0_ = (int)floorf(gx_);                                 \
            const int y0_ = (int)floorf(gy_);                                 \
            const int x1_ = x0_ + 1, y1_ = y0_ + 1;                           \
            const bool vx0 = (unsigned)x0_ < (unsigned)Wv;                    \
            const bool vx1 = (unsigned)x1_ < (unsigned)Wv;                    \
            const bool vy0 = (unsigned)y0_ < (unsigned)Hv;                    \
            const bool vy1 = (unsigned)y1_ < (unsigned)Hv;                    \
            const int cx0 = min(max(x0_, 0), Wv - 1);                         \
            const int cx1 = min(max(x1_, 0), Wv - 1);                         \
            const int cy0 = min(max(y0_, 0), Hv - 1);                         \
            const int cy1 = min(max(y1_, 0), Hv - 1);                         \
            _Pragma("unroll") for (int c = 0; c < CPB; ++c) {                 \
                const float* f = fbase + (size_t)c * HWsz;                    \
                ((float*)&T[0])[c] = (vx0 & vy0) ? f[cy0 * Wv + cx0] : 0.0f;  \
                ((float*)&T[1])[c] = (vx1 & vy0) ? f[cy0 * Wv + cx1] : 0.0f;  \
                ((float*)&T[2])[c] = (vx0 & vy1) ? f[cy1 * Wv + cx0] : 0.0f;  \
                ((float*)&T[3])[c] = (vx1 & vy1) ? f[cy1 * Wv + cx1] : 0.0f;  \
            }                                                                 \
        }                                                                     \
        _Pragma("unroll") for (int c = 0; c < CPB; ++c) {                     \
            const float r_ = ((const float*)&T[0])[c] * w00[K] +              \
                             ((const float*)&T[1])[c] * w10[K] +              \
                             ((const float*)&T[2])[c] * w01[K] +              \
                             ((const float*)&T[3])[c] * w11[K];               \
            __builtin_nontemporal_store(r_, &ob[(size_t)c * HWsz + pixk[K]]); \
        }                                                                     \
    } while (0)

    float4 tA[4], tB[4];
    READ(tA, 0);
    READ(tB, 1);
    CONSUME(tA, 0);
    READ(tA, 2);
    CONSUME(tB, 1);
    READ(tB, 3);
    CONSUME(tA, 2);
    CONSUME(tB, 3);

#undef READ
#undef CONSUME
}

extern "C" void kernel_launch(void* const* d_in, const int* in_sizes, int n_in,
                              void* d_out, int out_size, void* d_ws, size_t ws_size,
                              hipStream_t stream) {
    const float* feature = (const float*)d_in[0];
    const float* flow = (const float*)d_in[1];
    float* out = (float*)d_out;

    static bool inited = false;
    if (!inited) {
        hipFuncSetAttribute((const void*)resample2d_kernel,
                            hipFuncAttributeMaxDynamicSharedMemorySize, LDS_BYTES);
        inited = true;
    }

    dim3 block(THREADS, 1, 1);
    dim3 grid(NBLK, 1, 1);
    resample2d_kernel<<<grid, block, LDS_BYTES, stream>>>(feature, flow, out);
}

// Round 3
// 428.193 us; speedup vs baseline: 1.4863x; 1.0919x over previous
//
#include <hip/hip_runtime.h>

// Resample2d (Flownet2-style) bilinear warp.
// feature: [B,C,H,W] fp32, flow: [B,2,H,W] fp32, out: [B,C,H,W] fp32.
//
// R4: kill the LDS bank-conflict serialization found in R3's counters
// (5.25e7 conflict cycles = 40% of runtime; b128 gathers have only 8
// bank-groups -> ~13-way collisions under random flow). Changes:
//  - CPB 4->2, float2-interleaved sites (8B), odd stride SW=91: gathers are
//    ds_read2_b64-class with 16 bank-groups -> expected conflict multiplicity
//    halves. One 8B read still serves 2 channels; x-adjacent taps fuse.
//  - LDS 126.7KB -> 64.1KB: 2 blocks/CU co-resident (32 waves/CU),
//    __launch_bounds__(1024,8); block n+1's staging overlaps block n's
//    compute, removing the single-block barrier bubble (Occupancy 39%).
//  - Keep: hoisted flow loads, precomputed weights/addresses above the
//    barrier, 2-deep LDS pipeline, rare global fallback (execz-skipped),
//    nontemporal stores, XCD-chunked swizzle.

#define Bv 2
#define Cv 64
#define Hv 512
#define Wv 896
#define HWsz (Hv * Wv)

#define TILE 64
#define CPB 2                  // channels per block (one float2 site in LDS)
#define NCG (Cv / CPB)         // 32 channel groups
#define SW 91                  // staged cols; ODD -> bank-group mixing
#define SH 88                  // staged rows
#define XOFF 12                // xs = tx0 - 12  (x0 in [tx0-12, tx0+77])
#define YOFF 11                // ys = ty0 - 11  (y0 in [ty0-11, ty0+75])
#define NSITES (SH * SW)       // 8008
#define NTX (Wv / TILE)        // 14
#define NTY (Hv / TILE)        // 8
#define NTILES (NTX * NTY)     // 112
#define NBLK (Bv * NCG * NTILES)  // 7168 (div by 8 -> bijective XCD swizzle)
#define THREADS 1024
#define NW (THREADS / 64)      // 16 waves
#define KITERS (TILE * TILE / THREADS)  // 4 pixel-iterations per thread

__global__ __launch_bounds__(THREADS, 8) void resample2d_kernel(
    const float* __restrict__ feature,
    const float* __restrict__ flow,
    float* __restrict__ out) {
    __shared__ float2 smem[NSITES];  // 64,064 B -> 2 blocks/CU

    // XCD-chunked swizzle (bijective: NBLK % 8 == 0): consecutive wids share
    // channel planes + adjacent tiles -> halo re-reads are same-XCD L2 hits.
    const int orig = blockIdx.x;
    const int wid = (orig & 7) * (NBLK / 8) + (orig >> 3);
    const int txi = wid % NTX;
    const int t2 = wid / NTX;
    const int tyi = t2 % NTY;
    const int zb = t2 / NTY;
    const int b = zb / NCG;
    const int c0 = (zb % NCG) * CPB;

    const int tx0 = txi * TILE;
    const int ty0 = tyi * TILE;
    const int xs = tx0 - XOFF;
    const int ys = ty0 - YOFF;

    const int tid = threadIdx.x;
    const int lane = tid & 63;
    const int wv = tid >> 6;

    const float* __restrict__ fbase = feature + ((size_t)b * Cv + c0) * HWsz;
    const float* __restrict__ flb = flow + (size_t)b * 2 * HWsz;
    float* __restrict__ ob = out + ((size_t)b * Cv + c0) * HWsz;

    // ---- Phase A: issue flow loads for all KITERS rows (independent of LDS;
    // latency hides under the staging loop).
    const int px = tx0 + lane;
    float u[KITERS], v[KITERS];
#pragma unroll
    for (int k = 0; k < KITERS; ++k) {
        const int y = ty0 + wv + NW * k;
        const int pix = y * Wv + px;
        u[k] = flb[pix];
        v[k] = flb[HWsz + pix];
    }

    // ---- Phase B: stage 2 channel planes, float2-interleaved.
    // One site per lane: consecutive lanes -> consecutive 8B ds_write_b64
    // (2-way bank aliasing = free). Global loads coalesced per row segment.
    const bool interior = (xs >= 0) & (xs + SW <= Wv) & (ys >= 0) & (ys + SH <= Hv);
    if (interior) {
#pragma unroll
        for (int k = 0; k < 8; ++k) {
            const int p = tid + THREADS * k;
            if (p < NSITES) {
                const int r = p / SW;
                const int xx = p - r * SW;
                const float* src = fbase + (size_t)(ys + r) * Wv + (xs + xx);
                float2 val;
                val.x = src[0];
                val.y = src[HWsz];
                smem[p] = val;
            }
        }
    } else {
        // edge tiles: zero-fill out-of-image cells (== reference's
        // zero-weight semantics for OOB taps)
#pragma unroll
        for (int k = 0; k < 8; ++k) {
            const int p = tid + THREADS * k;
            if (p < NSITES) {
                const int r = p / SW;
                const int xx = p - r * SW;
                const int gy = ys + r;
                const int gx = xs + xx;
                float2 val = make_float2(0.0f, 0.0f);
                if (((unsigned)gy < (unsigned)Hv) & ((unsigned)gx < (unsigned)Wv)) {
                    const float* src = fbase + (size_t)gy * Wv + gx;
                    val.x = src[0];
                    val.y = src[HWsz];
                }
                smem[p] = val;
            }
        }
    }

    // ---- Phase C: frac weights + clamped LDS site addresses (no LDS dep;
    // overlaps the staging drain). inwin packed into one bitmask VGPR.
    float wx[KITERS], wy[KITERS];
    int ac[KITERS];
    unsigned iw = 0;
#pragma unroll
    for (int k = 0; k < KITERS; ++k) {
        const int y = ty0 + wv + NW * k;
        const float gx = u[k] + (float)px;
        const float gy = v[k] + (float)y;
        const float x0f = floorf(gx);
        const float y0f = floorf(gy);
        wx[k] = gx - x0f;
        wy[k] = gy - y0f;
        const int lx = (int)x0f - xs;
        const int ly = (int)y0f - ys;
        const bool inwin = ((unsigned)lx <= (unsigned)(SW - 2)) &
                           ((unsigned)ly <= (unsigned)(SH - 2));
        iw |= inwin ? (1u << k) : 0u;
        const int lxc = min(max(lx, 0), SW - 2);
        const int lyc = min(max(ly, 0), SH - 2);
        ac[k] = lyc * SW + lxc;  // site index; always in-bounds
    }

    __syncthreads();

    // ---- Phase D: 2-deep pipelined gather+combine.
    // READ: 4 float2 taps = 2x ds_read2_b64 (16 bank-groups each).
#define READ(T, K)                        \
    do {                                  \
        const int a_ = ac[K];             \
        T[0] = smem[a_];                  \
        T[1] = smem[a_ + 1];              \
        T[2] = smem[a_ + SW];             \
        T[3] = smem[a_ + SW + 1];         \
    } while (0)

#define CONSUME(T, K)                                                          \
    do {                                                                       \
        if (!(iw & (1u << (K)))) { /* rare Gaussian-tail fallback */           \
            const int y_ = ty0 + wv + NW * (K);                                \
            const float gx_ = u[K] + (float)px;                                \
            const float gy_ = v[K] + (float)y_;                                \
            const int x0_ = (int)floorf(gx_);                                  \
            const int y0_ = (int)floorf(gy_);                                  \
            const int x1_ = x0_ + 1, y1_ = y0_ + 1;                            \
            const bool vx0 = (unsigned)x0_ < (unsigned)Wv;                     \
            const bool vx1 = (unsigned)x1_ < (unsigned)Wv;                     \
            const bool vy0 = (unsigned)y0_ < (unsigned)Hv;                     \
            const bool vy1 = (unsigned)y1_ < (unsigned)Hv;                     \
            const int cx0 = min(max(x0_, 0), Wv - 1);                          \
            const int cx1 = min(max(x1_, 0), Wv - 1);                          \
            const int cy0 = min(max(y0_, 0), Hv - 1);                          \
            const int cy1 = min(max(y1_, 0), Hv - 1);                          \
            _Pragma("unroll") for (int c = 0; c < CPB; ++c) {                  \
                const float* f = fbase + (size_t)c * HWsz;                     \
                ((float*)&T[0])[c] = (vx0 & vy0) ? f[cy0 * Wv + cx0] : 0.0f;   \
                ((float*)&T[1])[c] = (vx1 & vy0) ? f[cy0 * Wv + cx1] : 0.0f;   \
                ((float*)&T[2])[c] = (vx0 & vy1) ? f[cy1 * Wv + cx0] : 0.0f;   \
                ((float*)&T[3])[c] = (vx1 & vy1) ? f[cy1 * Wv + cx1] : 0.0f;   \
            }                                                                  \
        }                                                                      \
        const float omx = 1.0f - wx[K];                                        \
        const float omy = 1.0f - wy[K];                                        \
        const float w00 = omx * omy;                                           \
        const float w10 = wx[K] * omy;                                         \
        const float w01 = omx * wy[K];                                         \
        const float w11 = wx[K] * wy[K];                                       \
        const int pix_ = (ty0 + wv + NW * (K)) * Wv + px;                      \
        const float r0 = T[0].x * w00 + T[1].x * w10 +                         \
                         T[2].x * w01 + T[3].x * w11;                          \
        const float r1 = T[0].y * w00 + T[1].y * w10 +                         \
                         T[2].y * w01 + T[3].y * w11;                          \
        __builtin_nontemporal_store(r0, &ob[pix_]);                            \
        __builtin_nontemporal_store(r1, &ob[HWsz + pix_]);                     \
    } while (0)

    float2 tA[4], tB[4];
    READ(tA, 0);
    READ(tB, 1);
    CONSUME(tA, 0);
    READ(tA, 2);
    CONSUME(tB, 1);
    READ(tB, 3);
    CONSUME(tA, 2);
    CONSUME(tB, 3);

#undef READ
#undef CONSUME
}

extern "C" void kernel_launch(void* const* d_in, const int* in_sizes, int n_in,
                              void* d_out, int out_size, void* d_ws, size_t ws_size,
                              hipStream_t stream) {
    const float* feature = (const float*)d_in[0];
    const float* flow = (const float*)d_in[1];
    float* out = (float*)d_out;

    dim3 block(THREADS, 1, 1);
    dim3 grid(NBLK, 1, 1);
    resample2d_kernel<<<grid, block, 0, stream>>>(feature, flow, out);
}

// Round 4
// 425.274 us; speedup vs baseline: 1.4965x; 1.0069x over previous
//
#include <hip/hip_runtime.h>

// Resample2d (Flownet2-style) bilinear warp.
// feature: [B,C,H,W] fp32, flow: [B,2,H,W] fp32, out: [B,C,H,W] fp32.
//
// R5: amortize per-pixel work across channel groups + explicit double-buffer
// pipeline. R4's counters (VALU 30%, HBM 34%, LDS ~30%, nothing saturated,
// 229 cyc/wave-iter vs ~140 issue) showed dependency stalls plus 32x-repeated
// per-pixel overhead (flow loads, weights, window checks, staging addressing
// recomputed per 2-channel group). Changes:
//  - GPB=4 groups (8 channels) per block, SAME tile: flow/weights/addresses
//    computed ONCE, reused 4x. Double-buffered LDS (2 x 64,064 B).
//  - Explicit pipeline per group: issue stage loads(g+1) -> compute(g) ->
//    ds_write(g+1) -> barrier. Stage-load latency hides under compute.
//  - Grid 1792 = exactly 7 blocks/CU; flow L2 re-fetch /4.
//  - Branch-free staging: per-thread gOff/sOff/vmask precomputed once;
//    p>=NSITES lanes clamp to last site (duplicate identical writes, benign).
//  - Keep: CPB=2 float2 sites, odd SW=91 (R4's conflict fix), rare global
//    fallback (execz-skipped), nontemporal stores, bijective XCD swizzle.

#define Bv 2
#define Cv 64
#define Hv 512
#define Wv 896
#define HWsz (Hv * Wv)

#define TILE 64
#define CPB 2                    // channels per LDS site (float2)
#define GPB 4                    // channel-groups per block -> 8 channels
#define NCG (Cv / CPB)           // 32
#define NCGB (NCG / GPB)         // 8 group-batches
#define SW 91                    // staged cols; ODD -> bank mixing
#define SH 88                    // staged rows
#define XOFF 12
#define YOFF 11
#define NSITES (SH * SW)         // 8008
#define NTX (Wv / TILE)          // 14
#define NTY (Hv / TILE)          // 8
#define NTILES (NTX * NTY)       // 112
#define NBLK (Bv * NCGB * NTILES)  // 1792 = 7*256, %8==0
#define THREADS 1024
#define NW (THREADS / 64)        // 16 waves
#define KITERS (TILE * TILE / THREADS)      // 4 pixel-iters/thread
#define SITE_ITERS ((NSITES + THREADS - 1) / THREADS)  // 8
#define LDS_BYTES (2 * NSITES * (int)sizeof(float2))   // 128,128 B

__global__ __launch_bounds__(THREADS, 4) void resample2d_kernel(
    const float* __restrict__ feature,
    const float* __restrict__ flow,
    float* __restrict__ out) {
    extern __shared__ float2 smem[];  // [2][NSITES]
    float2* const buf0 = smem;
    float2* const buf1 = smem + NSITES;

    // Bijective XCD-chunked swizzle (NBLK % 8 == 0): consecutive wids are
    // adjacent tiles of the same channel planes -> halo re-reads are L2 hits.
    const int orig = blockIdx.x;
    const int wid = (orig & 7) * (NBLK / 8) + (orig >> 3);
    const int txi = wid % NTX;
    const int t2 = wid / NTX;
    const int tyi = t2 % NTY;
    const int zb = t2 / NTY;        // (b, group-batch)
    const int b = zb / NCGB;
    const int c0 = (zb % NCGB) * (GPB * CPB);

    const int tx0 = txi * TILE;
    const int ty0 = tyi * TILE;
    const int xs = tx0 - XOFF;
    const int ys = ty0 - YOFF;

    const int tid = threadIdx.x;
    const int lane = tid & 63;
    const int wv = tid >> 6;

    const float* __restrict__ fbase = feature + ((size_t)b * Cv + c0) * HWsz;
    const float* __restrict__ flb = flow + (size_t)b * 2 * HWsz;
    float* __restrict__ ob = out + ((size_t)b * Cv + c0) * HWsz;

    // ---- A: flow loads (latency hides under site precompute + stage loads)
    const int px = tx0 + lane;
    float u[KITERS], v[KITERS];
    int pixk[KITERS];
#pragma unroll
    for (int k = 0; k < KITERS; ++k) {
        const int y = ty0 + wv + NW * k;
        pixk[k] = y * Wv + px;
        u[k] = flb[pixk[k]];
        v[k] = flb[HWsz + pixk[k]];
    }

    // ---- Per-thread staging-site precompute (ONCE; reused for all groups).
    // Lanes with p >= NSITES clamp to the last site: they load/write the same
    // data as the owner lane -> duplicate identical LDS writes, benign.
    int sOff[SITE_ITERS];
    int gOff[SITE_ITERS];
    float vmask[SITE_ITERS];
#pragma unroll
    for (int i = 0; i < SITE_ITERS; ++i) {
        const int p = tid + THREADS * i;
        const int pc = (p < NSITES) ? p : (NSITES - 1);
        const int r = pc / SW;
        const int xx = pc - r * SW;
        const int gy = ys + r;
        const int gx = xs + xx;
        const bool vd = ((unsigned)gy < (unsigned)Hv) & ((unsigned)gx < (unsigned)Wv);
        gOff[i] = vd ? (gy * Wv + gx) : 0;
        vmask[i] = vd ? 1.0f : 0.0f;
        sOff[i] = pc;
    }

#define STAGE_LOAD(G)                                            \
    do {                                                         \
        const float* __restrict__ fg_ =                          \
            fbase + (size_t)(G) * CPB * HWsz;                    \
        _Pragma("unroll") for (int i = 0; i < SITE_ITERS; ++i) { \
            a0[i] = fg_[gOff[i]];                                \
            a1[i] = fg_[gOff[i] + HWsz];                         \
        }                                                        \
    } while (0)

#define STAGE_WRITE(BUF)                                                   \
    do {                                                                   \
        _Pragma("unroll") for (int i = 0; i < SITE_ITERS; ++i) {           \
            BUF[sOff[i]] = make_float2(a0[i] * vmask[i], a1[i] * vmask[i]); \
        }                                                                  \
    } while (0)

    float a0[SITE_ITERS], a1[SITE_ITERS];
    STAGE_LOAD(0);

    // ---- C: weights + clamped LDS site addresses (ONCE; no LDS dep; VALU
    // overlaps the in-flight stage loads). Full 4-weight precompute: reused
    // by all GPB groups.
    float w00k[KITERS], w10k[KITERS], w01k[KITERS], w11k[KITERS];
    int ac[KITERS];
    unsigned iw = 0;
#pragma unroll
    for (int k = 0; k < KITERS; ++k) {
        const int y = ty0 + wv + NW * k;
        const float gx = u[k] + (float)px;
        const float gy = v[k] + (float)y;
        const float x0f = floorf(gx);
        const float y0f = floorf(gy);
        const float wx = gx - x0f;
        const float wy = gy - y0f;
        const float omx = 1.0f - wx;
        const float omy = 1.0f - wy;
        w00k[k] = omx * omy;
        w10k[k] = wx * omy;
        w01k[k] = omx * wy;
        w11k[k] = wx * wy;
        const int lx = (int)x0f - xs;
        const int ly = (int)y0f - ys;
        const bool inwin = ((unsigned)lx <= (unsigned)(SW - 2)) &
                           ((unsigned)ly <= (unsigned)(SH - 2));
        iw |= inwin ? (1u << k) : 0u;
        const int lxc = min(max(lx, 0), SW - 2);
        const int lyc = min(max(ly, 0), SH - 2);
        ac[k] = lyc * SW + lxc;
    }

#define COMPUTE(G, BUF)                                                        \
    do {                                                                       \
        float* __restrict__ og_ = ob + (size_t)(G) * CPB * HWsz;               \
        const float* __restrict__ fg_ = fbase + (size_t)(G) * CPB * HWsz;      \
        _Pragma("unroll") for (int k = 0; k < KITERS; ++k) {                   \
            float2 t00 = BUF[ac[k]];                                           \
            float2 t10 = BUF[ac[k] + 1];                                       \
            float2 t01 = BUF[ac[k] + SW];                                      \
            float2 t11 = BUF[ac[k] + SW + 1];                                  \
            if (!(iw & (1u << k))) { /* rare Gaussian-tail fallback */         \
                const int y_ = ty0 + wv + NW * k;                              \
                const float gx_ = u[k] + (float)px;                            \
                const float gy_ = v[k] + (float)y_;                            \
                const int x0_ = (int)floorf(gx_);                              \
                const int y0_ = (int)floorf(gy_);                              \
                const int x1_ = x0_ + 1, y1_ = y0_ + 1;                        \
                const bool vx0 = (unsigned)x0_ < (unsigned)Wv;                 \
                const bool vx1 = (unsigned)x1_ < (unsigned)Wv;                 \
                const bool vy0 = (unsigned)y0_ < (unsigned)Hv;                 \
                const bool vy1 = (unsigned)y1_ < (unsigned)Hv;                 \
                const int cx0 = min(max(x0_, 0), Wv - 1);                      \
                const int cx1 = min(max(x1_, 0), Wv - 1);                      \
                const int cy0 = min(max(y0_, 0), Hv - 1);                      \
                const int cy1 = min(max(y1_, 0), Hv - 1);                      \
                _Pragma("unroll") for (int c = 0; c < CPB; ++c) {              \
                    const float* f = fg_ + (size_t)c * HWsz;                   \
                    ((float*)&t00)[c] = (vx0 & vy0) ? f[cy0 * Wv + cx0] : 0.f; \
                    ((float*)&t10)[c] = (vx1 & vy0) ? f[cy0 * Wv + cx1] : 0.f; \
                    ((float*)&t01)[c] = (vx0 & vy1) ? f[cy1 * Wv + cx0] : 0.f; \
                    ((float*)&t11)[c] = (vx1 & vy1) ? f[cy1 * Wv + cx1] : 0.f; \
                }                                                              \
            }                                                                  \
            const float r0 = t00.x * w00k[k] + t10.x * w10k[k] +               \
                             t01.x * w01k[k] + t11.x * w11k[k];                \
            const float r1 = t00.y * w00k[k] + t10.y * w10k[k] +               \
                             t01.y * w01k[k] + t11.y * w11k[k];                \
            __builtin_nontemporal_store(r0, &og_[pixk[k]]);                    \
            __builtin_nontemporal_store(r1, &og_[HWsz + pixk[k]]);             \
        }                                                                      \
    } while (0)

    // ---- Pipelined group loop (fully unrolled, static buffer indexing):
    // stage loads for g+1 are issued BEFORE compute(g); their latency hides
    // under the gather+FMA phase. One barrier per group.
    STAGE_WRITE(buf0);
    __syncthreads();

    STAGE_LOAD(1);
    COMPUTE(0, buf0);
    STAGE_WRITE(buf1);
    __syncthreads();

    STAGE_LOAD(2);
    COMPUTE(1, buf1);
    STAGE_WRITE(buf0);
    __syncthreads();

    STAGE_LOAD(3);
    COMPUTE(2, buf0);
    STAGE_WRITE(buf1);
    __syncthreads();

    COMPUTE(3, buf1);

#undef STAGE_LOAD
#undef STAGE_WRITE
#undef COMPUTE
}

extern "C" void kernel_launch(void* const* d_in, const int* in_sizes, int n_in,
                              void* d_out, int out_size, void* d_ws, size_t ws_size,
                              hipStream_t stream) {
    const float* feature = (const float*)d_in[0];
    const float* flow = (const float*)d_in[1];
    float* out = (float*)d_out;

    static bool inited = false;
    if (!inited) {
        hipFuncSetAttribute((const void*)resample2d_kernel,
                            hipFuncAttributeMaxDynamicSharedMemorySize, LDS_BYTES);
        inited = true;
    }

    dim3 block(THREADS, 1, 1);
    dim3 grid(NBLK, 1, 1);
    resample2d_kernel<<<grid, block, LDS_BYTES, stream>>>(feature, flow, out);
}